// Round 1
// baseline (7754.494 us; speedup 1.0000x reference)
//
#include <hip/hip_runtime.h>

#define H 181
#define G3 543          // 3*H gate rows
#define WSTRIDE 544     // padded row stride of w_padT [H][WSTRIDE]
#define T_LEN 1024
#define BB 4            // batch rows per block
#define NBLK 256        // 256 * 4 = 1024 batch
#define NTHR 576        // 9 waves; threads 0..542 own one gate column each

__global__ void transpose_whh(const float* __restrict__ w_hh,
                              float* __restrict__ w_padT) {
    int idx = blockIdx.x * blockDim.x + threadIdx.x;   // over H*WSTRIDE
    if (idx >= H * WSTRIDE) return;
    int k = idx / WSTRIDE;
    int g = idx % WSTRIDE;
    w_padT[idx] = (g < G3) ? w_hh[g * H + k] : 0.0f;
}

__device__ __forceinline__ float sigmoid_fast(float v) {
    return 1.0f / (1.0f + __expf(-v));
}
__device__ __forceinline__ float tanh_fast(float v) {
    // 1 - 2/(e^{2v}+1): handles +inf overflow -> 1, e->0 -> -1
    float e = __expf(2.0f * v);
    return 1.0f - 2.0f / (e + 1.0f);
}

__launch_bounds__(NTHR, 1)
__global__ void gru_persist(const float* __restrict__ x,
                            const float* __restrict__ w_ih,
                            const float* __restrict__ b_ih,
                            const float* __restrict__ b_hh,
                            const float* __restrict__ w_padT,
                            const float* __restrict__ w_fc,
                            const float* __restrict__ b_fc,
                            float* __restrict__ out) {
    __shared__ __align__(16) float h_s[H][BB];     // h[k][bb]
    __shared__ __align__(16) float gh_s[G3][BB];   // gh[g][bb]
    __shared__ float wih_s[G3];
    __shared__ float bih_s[G3];
    __shared__ float bhh_s[G3];
    __shared__ float xr_s[BB][T_LEN];              // the block's 4 x rows

    const int tid = threadIdx.x;
    const int b0  = blockIdx.x * BB;

    // ---- preload: x rows (flat contiguous copy), gate weights, h=0 ----
    {
        float*       xs = &xr_s[0][0];
        const float* xg = x + (size_t)b0 * T_LEN;   // x is [B, T, 1]
        for (int i = tid; i < BB * T_LEN; i += NTHR) xs[i] = xg[i];
    }
    for (int i = tid; i < G3; i += NTHR) {
        wih_s[i] = w_ih[i];
        bih_s[i] = b_ih[i];
        bhh_s[i] = b_hh[i];
    }
    {
        float* hs = &h_s[0][0];
        for (int i = tid; i < H * BB; i += NTHR) hs[i] = 0.0f;
    }
    __syncthreads();

    const int   g  = tid;                 // gate column owned by this thread
    const float* wp = w_padT + g;         // column pointer, stride WSTRIDE

    for (int t = 0; t < T_LEN; ++t) {
        // ---- Phase A: gh[g][0..3] = sum_k w_hh[g][k] * h[k][bb] ----
        if (g < G3) {
            float a0 = 0.f, a1 = 0.f, a2 = 0.f, a3 = 0.f;
            #pragma unroll 8
            for (int k = 0; k < H; ++k) {
                float  w  = wp[k * WSTRIDE];                  // L2-hit stream
                float4 hv = *(const float4*)&h_s[k][0];       // LDS broadcast
                a0 = fmaf(w, hv.x, a0);
                a1 = fmaf(w, hv.y, a1);
                a2 = fmaf(w, hv.z, a2);
                a3 = fmaf(w, hv.w, a3);
            }
            float4* ghp = (float4*)&gh_s[g][0];
            *ghp = make_float4(a0, a1, a2, a3);
        }
        __syncthreads();

        // ---- Phase B: gates + hidden update, in place ----
        for (int e = tid; e < H * BB; e += NTHR) {
            int j  = e >> 2;
            int bb = e & 3;
            float xv   = xr_s[bb][t];
            float gr   = fmaf(xv, wih_s[j],         bih_s[j])         + gh_s[j][bb]         + bhh_s[j];
            float gz   = fmaf(xv, wih_s[H + j],     bih_s[H + j])     + gh_s[H + j][bb]     + bhh_s[H + j];
            float gn_h = gh_s[2 * H + j][bb] + bhh_s[2 * H + j];
            float gn_i = fmaf(xv, wih_s[2 * H + j], bih_s[2 * H + j]);
            float r = sigmoid_fast(gr);
            float z = sigmoid_fast(gz);
            float n = tanh_fast(fmaf(r, gn_h, gn_i));
            float hold = h_s[j][bb];
            h_s[j][bb] = fmaf(z, hold - n, n);   // (1-z)*n + z*h
        }
        __syncthreads();
    }

    // ---- final FC: logits[b][c] = h . w_fc[c] + b_fc[c] ----
    if (tid < BB * 10) {
        int bb = tid / 10;
        int c  = tid % 10;
        float acc = b_fc[c];
        for (int j = 0; j < H; ++j)
            acc = fmaf(h_s[j][bb], w_fc[c * H + j], acc);
        out[(b0 + bb) * 10 + c] = acc;
    }
}

extern "C" void kernel_launch(void* const* d_in, const int* in_sizes, int n_in,
                              void* d_out, int out_size, void* d_ws, size_t ws_size,
                              hipStream_t stream) {
    const float* x    = (const float*)d_in[0];
    const float* w_ih = (const float*)d_in[1];
    const float* w_hh = (const float*)d_in[2];
    const float* b_ih = (const float*)d_in[3];
    const float* b_hh = (const float*)d_in[4];
    const float* w_fc = (const float*)d_in[5];
    const float* b_fc = (const float*)d_in[6];
    float* out = (float*)d_out;

    float* w_padT = (float*)d_ws;   // H*WSTRIDE floats = 394 KB

    int total = H * WSTRIDE;
    transpose_whh<<<(total + 255) / 256, 256, 0, stream>>>(w_hh, w_padT);
    gru_persist<<<NBLK, NTHR, 0, stream>>>(x, w_ih, b_ih, b_hh, w_padT,
                                           w_fc, b_fc, out);
}

// Round 2
// 1615.711 us; speedup vs baseline: 4.7994x; 4.7994x over previous
//
#include <hip/hip_runtime.h>

#define H 181
#define G3 543
#define T_LEN 1024
#define BB 16            // batch rows per block
#define NBLK 64          // 64 * 16 = 1024
#define NTHR 768         // 12 waves
#define KT 6             // K tiles of 32 -> 192 >= 181
#define HBS 200          // h_bf row stride in bf16 units (400 B = 25*16: aligned, 2-way banks)
#define JP 192           // padded hidden dim

typedef __attribute__((ext_vector_type(8))) short short8;
typedef __attribute__((ext_vector_type(4))) float floatx4;

__device__ __forceinline__ unsigned short f2bf(float f) {
    unsigned u = __float_as_uint(f);
    u += 0x7fff + ((u >> 16) & 1);          // RNE; inputs are finite/bounded
    return (unsigned short)(u >> 16);
}
__device__ __forceinline__ float sigf(float v) { return 1.0f / (1.0f + __expf(-v)); }
__device__ __forceinline__ float tanh_fast(float v) {
    float e = __expf(2.0f * v);             // +inf -> 1, 0 -> -1: saturates correctly
    return 1.0f - 2.0f / (e + 1.0f);
}

// Persistent GRU block: 16 batch rows, 12 waves.
// Padded-N gate space: p = gate*192 + j (gate 0=r,1=z,2=n; j = hidden unit 0..191).
// Wave wv owns n-tiles {wv, wv+12, wv+24} -> its lane (col,q) holds, after MFMA,
// acc[r] = gh_gate[batch=q*4+r][j=16*wv+col] for all three gates. Gates are then
// applied entirely in registers; only h (bf16) round-trips through LDS.
__launch_bounds__(NTHR, 3)
__global__ void gru_mfma(const float* __restrict__ x,
                         const float* __restrict__ w_ih,
                         const float* __restrict__ w_hh,
                         const float* __restrict__ b_ih,
                         const float* __restrict__ b_hh,
                         const float* __restrict__ w_fc,
                         const float* __restrict__ b_fc,
                         float* __restrict__ out) {
    __shared__ __align__(16) unsigned short hbf_s[2][16 * HBS];  // double-buffered h (bf16)
    __shared__ __align__(16) float x_s[T_LEN * 16];              // x transposed [t][bb]
    __shared__ __align__(16) float hfin_s[16 * JP];              // final h (fp32) for FC

    const int tid  = threadIdx.x;
    const int wv   = tid >> 6;
    const int lane = tid & 63;
    const int col  = lane & 15;
    const int q    = lane >> 4;
    const int b0   = blockIdx.x * BB;
    const int j    = wv * 16 + col;        // hidden unit owned by this lane (0..191)
    const bool jv  = (j < H);

    // ---- B fragments (w_hh^T, bf16) in registers: 3 gates x 6 k-tiles ----
    // B[k][n=p]: lane holds n = tile*16+col, k = kt*32 + q*8 + e (e=0..7)
    short8 bfr[3][KT];
    #pragma unroll
    for (int i = 0; i < 3; ++i) {
        const int g = i * H + j;           // original gate row of w_hh [543][181]
        #pragma unroll
        for (int kt = 0; kt < KT; ++kt) {
            short8 f;
            #pragma unroll
            for (int e = 0; e < 8; ++e) {
                int k = kt * 32 + q * 8 + e;
                float v = (jv && k < H) ? w_hh[g * H + k] : 0.0f;
                f[e] = (short)f2bf(v);
            }
            bfr[i][kt] = f;
        }
    }
    // ---- per-lane gate weights/biases (I=1: gi is scalar fma) ----
    float wr = 0, wz = 0, wn = 0, brz = 0, bzz = 0, bin = 0, bhn = 0;
    if (jv) {
        wr  = w_ih[j]; wz = w_ih[H + j]; wn = w_ih[2 * H + j];
        brz = b_ih[j] + b_hh[j];
        bzz = b_ih[H + j] + b_hh[H + j];
        bin = b_ih[2 * H + j];
        bhn = b_hh[2 * H + j];
    }
    // ---- stage x into [t][bb] (init-only; uncoalesced reads are fine once) ----
    for (int i = tid; i < T_LEN * 16; i += NTHR) {
        int t = i >> 4, bb = i & 15;
        x_s[i] = x[(size_t)(b0 + bb) * T_LEN + t];
    }
    // zero h buffer 0 (incl. k-pad region)
    for (int i = tid; i < 16 * HBS; i += NTHR) hbf_s[0][i] = 0;
    __syncthreads();

    float h[4] = {0.f, 0.f, 0.f, 0.f};     // h[batch = q*4+r][j], persistent in regs

    for (int t = 0; t < T_LEN; ++t) {
        const unsigned short* rb = hbf_s[t & 1];
        unsigned short*       wb = hbf_s[(t + 1) & 1];

        floatx4 aR = {0.f, 0.f, 0.f, 0.f};
        floatx4 aZ = {0.f, 0.f, 0.f, 0.f};
        floatx4 aN = {0.f, 0.f, 0.f, 0.f};
        #pragma unroll
        for (int kt = 0; kt < KT; ++kt) {
            // A fragment: m = col (batch), k = kt*32 + q*8 + e
            short8 a = *(const short8*)&rb[col * HBS + kt * 32 + q * 8];
            aR = __builtin_amdgcn_mfma_f32_16x16x32_bf16(a, bfr[0][kt], aR, 0, 0, 0);
            aZ = __builtin_amdgcn_mfma_f32_16x16x32_bf16(a, bfr[1][kt], aZ, 0, 0, 0);
            aN = __builtin_amdgcn_mfma_f32_16x16x32_bf16(a, bfr[2][kt], aN, 0, 0, 0);
        }
        floatx4 xv = *(const floatx4*)&x_s[t * 16 + q * 4];   // x for bb = q*4..q*4+3

        #pragma unroll
        for (int r = 0; r < 4; ++r) {
            float gr = aR[r] + fmaf(xv[r], wr, brz);
            float gz = aZ[r] + fmaf(xv[r], wz, bzz);
            float rr = sigf(gr);
            float zz = sigf(gz);
            float nn = tanh_fast(fmaf(rr, aN[r] + bhn, fmaf(xv[r], wn, bin)));
            h[r] = nn + zz * (h[r] - nn);                      // (1-z)*n + z*h
            wb[(q * 4 + r) * HBS + j] = f2bf(h[r]);
        }
        __syncthreads();   // writes of t visible before reads of t+1; reads of t done
    }

    // ---- final FC from registers via LDS ----
    #pragma unroll
    for (int r = 0; r < 4; ++r)
        hfin_s[(q * 4 + r) * JP + j] = h[r];
    __syncthreads();
    if (tid < BB * 10) {
        int bb = tid / 10, c = tid % 10;
        float acc = b_fc[c];
        for (int jj = 0; jj < H; ++jj)
            acc = fmaf(hfin_s[bb * JP + jj], w_fc[c * H + jj], acc);
        out[(b0 + bb) * 10 + c] = acc;
    }
}

extern "C" void kernel_launch(void* const* d_in, const int* in_sizes, int n_in,
                              void* d_out, int out_size, void* d_ws, size_t ws_size,
                              hipStream_t stream) {
    const float* x    = (const float*)d_in[0];
    const float* w_ih = (const float*)d_in[1];
    const float* w_hh = (const float*)d_in[2];
    const float* b_ih = (const float*)d_in[3];
    const float* b_hh = (const float*)d_in[4];
    const float* w_fc = (const float*)d_in[5];
    const float* b_fc = (const float*)d_in[6];
    float* out = (float*)d_out;

    gru_mfma<<<NBLK, NTHR, 0, stream>>>(x, w_ih, w_hh, b_ih, b_hh, w_fc, b_fc, out);
}